// Round 5
// baseline (349.108 us; speedup 1.0000x reference)
//
#include <hip/hip_runtime.h>
#include <cstddef>

#define NN 12288
#define FD 512
#define H1 32
#define H2 16

typedef float floatx4 __attribute__((ext_vector_type(4)));

// ---------------- P = feat @ W1 (unscaled); also zeroes deg arrays ----------------
__global__ __launch_bounds__(256) void k_gemm1(const float* __restrict__ feat,
                                               const float* __restrict__ W1,
                                               float* __restrict__ P,
                                               int* __restrict__ degz) {
    // fused zero of deg_out_cnt + deg_in (2*NN ints), covered by first 96 blocks
    int gz = blockIdx.x * 256 + threadIdx.x;
    if (gz < 2 * NN) degz[gz] = 0;

    __shared__ float Wlds[FD * H1]; // 64 KB, k-major [k][c]
    int tid = threadIdx.x;
    for (int t = tid; t < FD * H1 / 4; t += 256) {
        ((float4*)Wlds)[t] = ((const float4*)W1)[t];
    }
    __syncthreads();

    int row = blockIdx.x * 64 + (tid >> 2);
    int cg  = (tid & 3) * 8;
    float acc[8] = {};
    const float4* f4 = (const float4*)(feat + (size_t)row * FD);
#pragma unroll 4
    for (int k4 = 0; k4 < FD / 4; ++k4) {
        float4 f = f4[k4];
        const float* w = &Wlds[(k4 * 4) * H1 + cg];
#pragma unroll
        for (int j = 0; j < 8; ++j) {
            acc[j] += f.x * w[j] + f.y * w[H1 + j] + f.z * w[2 * H1 + j] + f.w * w[3 * H1 + j];
        }
    }
#pragma unroll
    for (int j = 0; j < 8; ++j) P[(size_t)row * H1 + cg + j] = acc[j];
}

// ---------------- degree histograms (int atomics) ----------------
__global__ void k_degree(const int* __restrict__ src, const int* __restrict__ dst,
                         int* __restrict__ deg_out, int* __restrict__ deg_in, int E) {
    int e = blockIdx.x * 256 + threadIdx.x;
    if (e < E) {
        atomicAdd(&deg_out[src[e]], 1);
        atomicAdd(&deg_in[dst[e]], 1);
    }
}

// ---------------- parallel scan + norms + zero cnt (single block, 1024 thr) -------
__global__ __launch_bounds__(1024) void k_scan(int* __restrict__ deg_out_cnt,
                                               const int* __restrict__ deg_in,
                                               int* __restrict__ row_ptr,
                                               float* __restrict__ n_src,
                                               float* __restrict__ n_dst) {
    __shared__ int wsum[16];
    int tid = threadIdx.x;
    const int CH = NN / 1024; // 12
    int base = tid * CH;
    int v[CH];
#pragma unroll
    for (int t = 0; t < CH; ++t) v[t] = deg_in[base + t];
    int s = 0;
#pragma unroll
    for (int t = 0; t < CH; ++t) { int x = v[t]; v[t] = s; s += x; }
    // inclusive wave scan over 64 lanes
    int lane = tid & 63;
    int incl = s;
#pragma unroll
    for (int off = 1; off < 64; off <<= 1) {
        int up = __shfl_up(incl, off);
        if (lane >= off) incl += up;
    }
    int wid = tid >> 6; // 16 waves
    if (lane == 63) wsum[wid] = incl;
    __syncthreads();
    if (tid == 0) {
        int a = 0;
        for (int w = 0; w < 16; ++w) { int x = wsum[w]; wsum[w] = a; a += x; }
    }
    __syncthreads();
    int excl = incl - s + wsum[wid];
#pragma unroll
    for (int t = 0; t < CH; ++t) row_ptr[base + t] = excl + v[t];
    if (tid == 1023) row_ptr[NN] = excl + s;

    // norms + zero cnt (self-loops guarantee deg >= 1)
#pragma unroll
    for (int t = 0; t < CH; ++t) {
        int i = base + t;
        n_src[i] = rsqrtf((float)deg_out_cnt[i]);
        n_dst[i] = rsqrtf((float)deg_in[i]);
        deg_out_cnt[i] = 0; // becomes cnt for scatter
    }
}

// ---------------- scatter edges into dst-sorted order ----------------
__global__ void k_scatter(const int* __restrict__ src, const int* __restrict__ dst,
                          const int* __restrict__ row_ptr, int* __restrict__ cnt,
                          int* __restrict__ sorted_src, int E) {
    int e = blockIdx.x * 256 + threadIdx.x;
    if (e < E) {
        int d = dst[e];
        int pos = row_ptr[d] + atomicAdd(&cnt[d], 1);
        sorted_src[pos] = src[e];
    }
}

// ---------------- agg1: CSR pull, per-edge n_src, fused ReLU epilogue ----------------
// h1s[i][j] = n_src[i] * relu(n_dst[i] * sum_e n_src[src_e] * P[src_e][j] + b1[j])
__global__ __launch_bounds__(256) void k_agg1(const int* __restrict__ row_ptr,
                                              const int* __restrict__ sorted_src,
                                              const float* __restrict__ P,
                                              const float* __restrict__ n_src,
                                              const float* __restrict__ n_dst,
                                              const float* __restrict__ b1,
                                              float* __restrict__ h1s) {
    int r = blockIdx.x * 8 + (threadIdx.x >> 5);
    int j = threadIdx.x & 31;
    int beg = row_ptr[r], end = row_ptr[r + 1];
    float s = 0.0f;
    int e = beg;
    for (; e + 3 < end; e += 4) {
        int s0 = sorted_src[e], s1 = sorted_src[e + 1];
        int s2 = sorted_src[e + 2], s3 = sorted_src[e + 3];
        float w0 = n_src[s0], w1 = n_src[s1], w2 = n_src[s2], w3 = n_src[s3];
        s += w0 * P[(size_t)s0 * H1 + j] + w1 * P[(size_t)s1 * H1 + j]
           + w2 * P[(size_t)s2 * H1 + j] + w3 * P[(size_t)s3 * H1 + j];
    }
    for (; e < end; ++e) {
        int s0 = sorted_src[e];
        s += n_src[s0] * P[(size_t)s0 * H1 + j];
    }
    float h = fmaxf(s * n_dst[r] + b1[j], 0.0f);
    h1s[(size_t)r * H1 + j] = h * n_src[r];
}

// ---------------- agg2: CSR pull + fused mu/logvar projection ----------------
__global__ __launch_bounds__(256) void k_agg2(const int* __restrict__ row_ptr,
                                              const int* __restrict__ sorted_src,
                                              const float* __restrict__ h1s,
                                              const float* __restrict__ n_dst,
                                              const float* __restrict__ W2, const float* __restrict__ b2,
                                              const float* __restrict__ W3, const float* __restrict__ b3,
                                              float* __restrict__ mu, float* __restrict__ lv) {
    __shared__ float W2l[H1 * H2], W3l[H1 * H2];
    __shared__ float S[8][H1];
    int tid = threadIdx.x;
    for (int t = tid; t < H1 * H2; t += 256) { W2l[t] = W2[t]; W3l[t] = W3[t]; }

    int r0 = blockIdx.x * 8;
    int rl = tid >> 5, j = tid & 31;
    int r = r0 + rl;
    int beg = row_ptr[r], end = row_ptr[r + 1];
    float s = 0.0f;
    int e = beg;
    for (; e + 3 < end; e += 4) {
        int s0 = sorted_src[e], s1 = sorted_src[e + 1];
        int s2 = sorted_src[e + 2], s3 = sorted_src[e + 3];
        s += h1s[(size_t)s0 * H1 + j] + h1s[(size_t)s1 * H1 + j]
           + h1s[(size_t)s2 * H1 + j] + h1s[(size_t)s3 * H1 + j];
    }
    for (; e < end; ++e) s += h1s[(size_t)sorted_src[e] * H1 + j];
    S[rl][j] = s * n_dst[r];
    __syncthreads();

    // 8 rows x 16 cols x {mu, lv} = 256 outputs, one per thread
    int rr = tid >> 5;
    int c = tid & 15;
    bool is_lv = (tid & 16) != 0;
    const float* W = is_lv ? W3l : W2l;
    float acc = is_lv ? b3[c] : b2[c];
#pragma unroll
    for (int k = 0; k < H1; ++k) acc += S[rr][k] * W[k * H2 + c];
    float* o = is_lv ? lv : mu;
    o[(size_t)(r0 + rr) * H2 + c] = acc;
}

// ---------------- adj = mu @ mu^T, 128x128 tile, k-major LDS, NT stores ------------
#define TILE 128
__global__ __launch_bounds__(256) void k_adj(const float* __restrict__ mu, float* __restrict__ out) {
    __shared__ float Alt[H2][TILE]; // k-major: fragment reads become ds_read_b128
    __shared__ float Blt[H2][TILE];
    int tid = threadIdx.x;
    int i0 = blockIdx.y * TILE;
    int j0 = blockIdx.x * TILE;

    {
        int row = tid >> 1;
        int h8  = (tid & 1) * 8;
        float4 a0 = *(const float4*)&mu[(size_t)(i0 + row) * H2 + h8];
        float4 a1 = *(const float4*)&mu[(size_t)(i0 + row) * H2 + h8 + 4];
        Alt[h8 + 0][row] = a0.x; Alt[h8 + 1][row] = a0.y; Alt[h8 + 2][row] = a0.z; Alt[h8 + 3][row] = a0.w;
        Alt[h8 + 4][row] = a1.x; Alt[h8 + 5][row] = a1.y; Alt[h8 + 6][row] = a1.z; Alt[h8 + 7][row] = a1.w;
        float4 b0 = *(const float4*)&mu[(size_t)(j0 + row) * H2 + h8];
        float4 b1 = *(const float4*)&mu[(size_t)(j0 + row) * H2 + h8 + 4];
        Blt[h8 + 0][row] = b0.x; Blt[h8 + 1][row] = b0.y; Blt[h8 + 2][row] = b0.z; Blt[h8 + 3][row] = b0.w;
        Blt[h8 + 4][row] = b1.x; Blt[h8 + 5][row] = b1.y; Blt[h8 + 6][row] = b1.z; Blt[h8 + 7][row] = b1.w;
    }
    __syncthreads();

    int tx = tid & 15;   // j (coalescing)
    int ty = tid >> 4;   // i
    float acc[8][8] = {};
#pragma unroll
    for (int k = 0; k < H2; ++k) {
        float4 a0 = *(const float4*)&Alt[k][ty * 8];
        float4 a1 = *(const float4*)&Alt[k][ty * 8 + 4];
        float4 b0 = *(const float4*)&Blt[k][tx * 8];
        float4 b1 = *(const float4*)&Blt[k][tx * 8 + 4];
        float a[8] = {a0.x, a0.y, a0.z, a0.w, a1.x, a1.y, a1.z, a1.w};
        float b[8] = {b0.x, b0.y, b0.z, b0.w, b1.x, b1.y, b1.z, b1.w};
#pragma unroll
        for (int ii = 0; ii < 8; ++ii)
#pragma unroll
            for (int jj = 0; jj < 8; ++jj) acc[ii][jj] += a[ii] * b[jj];
    }

#pragma unroll
    for (int ii = 0; ii < 8; ++ii) {
        size_t row = (size_t)(i0 + ty * 8 + ii);
        floatx4 v0 = {acc[ii][0], acc[ii][1], acc[ii][2], acc[ii][3]};
        floatx4 v1 = {acc[ii][4], acc[ii][5], acc[ii][6], acc[ii][7]};
        __builtin_nontemporal_store(v0, (floatx4*)&out[row * NN + j0 + tx * 8 + 0]);
        __builtin_nontemporal_store(v1, (floatx4*)&out[row * NN + j0 + tx * 8 + 4]);
    }
}

extern "C" void kernel_launch(void* const* d_in, const int* in_sizes, int n_in,
                              void* d_out, int out_size, void* d_ws, size_t ws_size,
                              hipStream_t stream) {
    const float* feat = (const float*)d_in[0];
    const int*   src  = (const int*)d_in[1];
    const int*   dst  = (const int*)d_in[2];
    const float* W1   = (const float*)d_in[3];
    const float* b1   = (const float*)d_in[4];
    const float* W2   = (const float*)d_in[5];
    const float* b2   = (const float*)d_in[6];
    const float* W3   = (const float*)d_in[7];
    const float* b3   = (const float*)d_in[8];
    int E = in_sizes[1]; // 405504

    int* iws = (int*)d_ws;
    int* deg_out_cnt = iws;                 // [NN]  (deg_out, reused as scatter cnt)
    int* deg_in      = iws + NN;            // [NN]
    int* row_ptr     = iws + 2 * NN;        // [NN+1] (padded to NN+64)
    int* sorted_src  = iws + 3 * NN + 64;   // [E]
    float* fws   = (float*)(iws + 3 * NN + 64 + E);
    float* n_src = fws;                     // [NN]
    float* n_dst = fws + NN;                // [NN]
    float* P     = fws + 2 * NN;            // [NN*H1] (unscaled feat@W1)
    float* h1s   = fws + 2 * NN + NN * H1;  // [NN*H1]

    float* adj = (float*)d_out;             // [NN*NN]
    float* mu  = adj + (size_t)NN * NN;     // [NN*H2]
    float* lv  = mu + (size_t)NN * H2;      // [NN*H2]

    int eb = (E + 255) / 256;
    k_gemm1<<<NN / 64, 256, 0, stream>>>(feat, W1, P, deg_out_cnt); // zeroes deg too
    k_degree<<<eb, 256, 0, stream>>>(src, dst, deg_out_cnt, deg_in, E);
    k_scan<<<1, 1024, 0, stream>>>(deg_out_cnt, deg_in, row_ptr, n_src, n_dst);
    k_scatter<<<eb, 256, 0, stream>>>(src, dst, row_ptr, deg_out_cnt, sorted_src, E);
    k_agg1<<<NN / 8, 256, 0, stream>>>(row_ptr, sorted_src, P, n_src, n_dst, b1, h1s);
    k_agg2<<<NN / 8, 256, 0, stream>>>(row_ptr, sorted_src, h1s, n_dst, W2, b2, W3, b3, mu, lv);

    dim3 grid(NN / TILE, NN / TILE);
    k_adj<<<grid, 256, 0, stream>>>(mu, adj);
}

// Round 6
// 250.361 us; speedup vs baseline: 1.3944x; 1.3944x over previous
//
#include <hip/hip_runtime.h>
#include <cstddef>

#define NN 12288
#define FD 512
#define H1 32
#define H2 16

typedef float floatx4 __attribute__((ext_vector_type(4)));
typedef float floatx2 __attribute__((ext_vector_type(2)));

// ---------------- P = feat @ W1 (unscaled); also zeroes deg arrays ----------------
__global__ __launch_bounds__(256) void k_gemm1(const float* __restrict__ feat,
                                               const float* __restrict__ W1,
                                               float* __restrict__ P,
                                               int* __restrict__ degz) {
    // fused zero of deg_out_cnt + deg_in (2*NN ints), covered by first 96 blocks
    int gz = blockIdx.x * 256 + threadIdx.x;
    if (gz < 2 * NN) degz[gz] = 0;

    __shared__ float Wlds[FD * H1]; // 64 KB, k-major [k][c]
    int tid = threadIdx.x;
    for (int t = tid; t < FD * H1 / 4; t += 256) {
        ((float4*)Wlds)[t] = ((const float4*)W1)[t];
    }
    __syncthreads();

    int row = blockIdx.x * 64 + (tid >> 2);
    int cg  = (tid & 3) * 8;
    float acc[8] = {};
    const float4* f4 = (const float4*)(feat + (size_t)row * FD);
#pragma unroll 4
    for (int k4 = 0; k4 < FD / 4; ++k4) {
        float4 f = f4[k4];
        const float* w = &Wlds[(k4 * 4) * H1 + cg];
#pragma unroll
        for (int j = 0; j < 8; ++j) {
            acc[j] += f.x * w[j] + f.y * w[H1 + j] + f.z * w[2 * H1 + j] + f.w * w[3 * H1 + j];
        }
    }
#pragma unroll
    for (int j = 0; j < 8; ++j) P[(size_t)row * H1 + cg + j] = acc[j];
}

// ---------------- degree histograms (int atomics) ----------------
__global__ void k_degree(const int* __restrict__ src, const int* __restrict__ dst,
                         int* __restrict__ deg_out, int* __restrict__ deg_in, int E) {
    int e = blockIdx.x * 256 + threadIdx.x;
    if (e < E) {
        atomicAdd(&deg_out[src[e]], 1);
        atomicAdd(&deg_in[dst[e]], 1);
    }
}

// ---------------- parallel scan + norms + zero cnt (single block, 1024 thr) -------
__global__ __launch_bounds__(1024) void k_scan(int* __restrict__ deg_out_cnt,
                                               const int* __restrict__ deg_in,
                                               int* __restrict__ row_ptr,
                                               float* __restrict__ n_src,
                                               float* __restrict__ n_dst) {
    __shared__ int wsum[16];
    int tid = threadIdx.x;
    const int CH = NN / 1024; // 12
    int base = tid * CH;
    int v[CH];
#pragma unroll
    for (int t = 0; t < CH; ++t) v[t] = deg_in[base + t];
    int s = 0;
#pragma unroll
    for (int t = 0; t < CH; ++t) { int x = v[t]; v[t] = s; s += x; }
    // inclusive wave scan over 64 lanes
    int lane = tid & 63;
    int incl = s;
#pragma unroll
    for (int off = 1; off < 64; off <<= 1) {
        int up = __shfl_up(incl, off);
        if (lane >= off) incl += up;
    }
    int wid = tid >> 6; // 16 waves
    if (lane == 63) wsum[wid] = incl;
    __syncthreads();
    if (tid == 0) {
        int a = 0;
        for (int w = 0; w < 16; ++w) { int x = wsum[w]; wsum[w] = a; a += x; }
    }
    __syncthreads();
    int excl = incl - s + wsum[wid];
#pragma unroll
    for (int t = 0; t < CH; ++t) row_ptr[base + t] = excl + v[t];
    if (tid == 1023) row_ptr[NN] = excl + s;

    // norms + zero cnt (self-loops guarantee deg >= 1)
#pragma unroll
    for (int t = 0; t < CH; ++t) {
        int i = base + t;
        n_src[i] = rsqrtf((float)deg_out_cnt[i]);
        n_dst[i] = rsqrtf((float)deg_in[i]);
        deg_out_cnt[i] = 0; // becomes cnt for scatter
    }
}

// ---------------- scatter edges into dst-sorted order ----------------
__global__ void k_scatter(const int* __restrict__ src, const int* __restrict__ dst,
                          const int* __restrict__ row_ptr, int* __restrict__ cnt,
                          int* __restrict__ sorted_src, int E) {
    int e = blockIdx.x * 256 + threadIdx.x;
    if (e < E) {
        int d = dst[e];
        int pos = row_ptr[d] + atomicAdd(&cnt[d], 1);
        sorted_src[pos] = src[e];
    }
}

// ---------------- agg1: CSR pull, per-edge n_src, fused ReLU epilogue ----------------
// h1s[i][j] = n_src[i] * relu(n_dst[i] * sum_e n_src[src_e] * P[src_e][j] + b1[j])
__global__ __launch_bounds__(256) void k_agg1(const int* __restrict__ row_ptr,
                                              const int* __restrict__ sorted_src,
                                              const float* __restrict__ P,
                                              const float* __restrict__ n_src,
                                              const float* __restrict__ n_dst,
                                              const float* __restrict__ b1,
                                              float* __restrict__ h1s) {
    int r = blockIdx.x * 8 + (threadIdx.x >> 5);
    int j = threadIdx.x & 31;
    int beg = row_ptr[r], end = row_ptr[r + 1];
    float s = 0.0f;
    int e = beg;
    for (; e + 3 < end; e += 4) {
        int s0 = sorted_src[e], s1 = sorted_src[e + 1];
        int s2 = sorted_src[e + 2], s3 = sorted_src[e + 3];
        float w0 = n_src[s0], w1 = n_src[s1], w2 = n_src[s2], w3 = n_src[s3];
        s += w0 * P[(size_t)s0 * H1 + j] + w1 * P[(size_t)s1 * H1 + j]
           + w2 * P[(size_t)s2 * H1 + j] + w3 * P[(size_t)s3 * H1 + j];
    }
    for (; e < end; ++e) {
        int s0 = sorted_src[e];
        s += n_src[s0] * P[(size_t)s0 * H1 + j];
    }
    float h = fmaxf(s * n_dst[r] + b1[j], 0.0f);
    h1s[(size_t)r * H1 + j] = h * n_src[r];
}

// ---------------- agg2: CSR pull + fused mu/logvar projection ----------------
__global__ __launch_bounds__(256) void k_agg2(const int* __restrict__ row_ptr,
                                              const int* __restrict__ sorted_src,
                                              const float* __restrict__ h1s,
                                              const float* __restrict__ n_dst,
                                              const float* __restrict__ W2, const float* __restrict__ b2,
                                              const float* __restrict__ W3, const float* __restrict__ b3,
                                              float* __restrict__ mu, float* __restrict__ lv) {
    __shared__ float W2l[H1 * H2], W3l[H1 * H2];
    __shared__ float S[8][H1];
    int tid = threadIdx.x;
    for (int t = tid; t < H1 * H2; t += 256) { W2l[t] = W2[t]; W3l[t] = W3[t]; }

    int r0 = blockIdx.x * 8;
    int rl = tid >> 5, j = tid & 31;
    int r = r0 + rl;
    int beg = row_ptr[r], end = row_ptr[r + 1];
    float s = 0.0f;
    int e = beg;
    for (; e + 3 < end; e += 4) {
        int s0 = sorted_src[e], s1 = sorted_src[e + 1];
        int s2 = sorted_src[e + 2], s3 = sorted_src[e + 3];
        s += h1s[(size_t)s0 * H1 + j] + h1s[(size_t)s1 * H1 + j]
           + h1s[(size_t)s2 * H1 + j] + h1s[(size_t)s3 * H1 + j];
    }
    for (; e < end; ++e) s += h1s[(size_t)sorted_src[e] * H1 + j];
    S[rl][j] = s * n_dst[r];
    __syncthreads();

    // 8 rows x 16 cols x {mu, lv} = 256 outputs, one per thread
    int rr = tid >> 5;
    int c = tid & 15;
    bool is_lv = (tid & 16) != 0;
    const float* W = is_lv ? W3l : W2l;
    float acc = is_lv ? b3[c] : b2[c];
#pragma unroll
    for (int k = 0; k < H1; ++k) acc += S[rr][k] * W[k * H2 + c];
    float* o = is_lv ? lv : mu;
    o[(size_t)(r0 + rr) * H2 + c] = acc;
}

// ---------------- adj = mu @ mu^T, 128x128 tile, k-major LDS, packed FMA ------------
#define TILE 128
__global__ __launch_bounds__(256) void k_adj(const float* __restrict__ mu, float* __restrict__ out) {
    __shared__ float Alt[H2][TILE]; // k-major: fragment reads are ds_read_b128
    __shared__ float Blt[H2][TILE];
    int tid = threadIdx.x;
    int i0 = blockIdx.y * TILE;
    int j0 = blockIdx.x * TILE;

    {
        int row = tid >> 1;
        int h8  = (tid & 1) * 8;
        float4 a0 = *(const float4*)&mu[(size_t)(i0 + row) * H2 + h8];
        float4 a1 = *(const float4*)&mu[(size_t)(i0 + row) * H2 + h8 + 4];
        Alt[h8 + 0][row] = a0.x; Alt[h8 + 1][row] = a0.y; Alt[h8 + 2][row] = a0.z; Alt[h8 + 3][row] = a0.w;
        Alt[h8 + 4][row] = a1.x; Alt[h8 + 5][row] = a1.y; Alt[h8 + 6][row] = a1.z; Alt[h8 + 7][row] = a1.w;
        float4 b0 = *(const float4*)&mu[(size_t)(j0 + row) * H2 + h8];
        float4 b1 = *(const float4*)&mu[(size_t)(j0 + row) * H2 + h8 + 4];
        Blt[h8 + 0][row] = b0.x; Blt[h8 + 1][row] = b0.y; Blt[h8 + 2][row] = b0.z; Blt[h8 + 3][row] = b0.w;
        Blt[h8 + 4][row] = b1.x; Blt[h8 + 5][row] = b1.y; Blt[h8 + 6][row] = b1.z; Blt[h8 + 7][row] = b1.w;
    }
    __syncthreads();

    int tx = tid & 15;   // j (coalescing)
    int ty = tid >> 4;   // i
    floatx2 acc2[8][4] = {};
#pragma unroll 2
    for (int k = 0; k < H2; ++k) {
        floatx4 a0 = *(const floatx4*)&Alt[k][ty * 8];
        floatx4 a1 = *(const floatx4*)&Alt[k][ty * 8 + 4];
        floatx4 b0 = *(const floatx4*)&Blt[k][tx * 8];
        floatx4 b1 = *(const floatx4*)&Blt[k][tx * 8 + 4];
        float a[8] = {a0.x, a0.y, a0.z, a0.w, a1.x, a1.y, a1.z, a1.w};
        floatx2 bp[4];
        bp[0] = (floatx2){b0.x, b0.y}; bp[1] = (floatx2){b0.z, b0.w};
        bp[2] = (floatx2){b1.x, b1.y}; bp[3] = (floatx2){b1.z, b1.w};
#pragma unroll
        for (int ii = 0; ii < 8; ++ii) {
            floatx2 av = (floatx2){a[ii], a[ii]};
#pragma unroll
            for (int jp = 0; jp < 4; ++jp)
                acc2[ii][jp] = __builtin_elementwise_fma(av, bp[jp], acc2[ii][jp]);
        }
    }

#pragma unroll
    for (int ii = 0; ii < 8; ++ii) {
        size_t row = (size_t)(i0 + ty * 8 + ii);
        float4 v0 = make_float4(acc2[ii][0].x, acc2[ii][0].y, acc2[ii][1].x, acc2[ii][1].y);
        float4 v1 = make_float4(acc2[ii][2].x, acc2[ii][2].y, acc2[ii][3].x, acc2[ii][3].y);
        *(float4*)&out[row * NN + j0 + tx * 8 + 0] = v0;
        *(float4*)&out[row * NN + j0 + tx * 8 + 4] = v1;
    }
}

extern "C" void kernel_launch(void* const* d_in, const int* in_sizes, int n_in,
                              void* d_out, int out_size, void* d_ws, size_t ws_size,
                              hipStream_t stream) {
    const float* feat = (const float*)d_in[0];
    const int*   src  = (const int*)d_in[1];
    const int*   dst  = (const int*)d_in[2];
    const float* W1   = (const float*)d_in[3];
    const float* b1   = (const float*)d_in[4];
    const float* W2   = (const float*)d_in[5];
    const float* b2   = (const float*)d_in[6];
    const float* W3   = (const float*)d_in[7];
    const float* b3   = (const float*)d_in[8];
    int E = in_sizes[1]; // 405504

    int* iws = (int*)d_ws;
    int* deg_out_cnt = iws;                 // [NN]  (deg_out, reused as scatter cnt)
    int* deg_in      = iws + NN;            // [NN]
    int* row_ptr     = iws + 2 * NN;        // [NN+1] (padded to NN+64)
    int* sorted_src  = iws + 3 * NN + 64;   // [E]
    float* fws   = (float*)(iws + 3 * NN + 64 + E);
    float* n_src = fws;                     // [NN]
    float* n_dst = fws + NN;                // [NN]
    float* P     = fws + 2 * NN;            // [NN*H1] (unscaled feat@W1)
    float* h1s   = fws + 2 * NN + NN * H1;  // [NN*H1]

    float* adj = (float*)d_out;             // [NN*NN]
    float* mu  = adj + (size_t)NN * NN;     // [NN*H2]
    float* lv  = mu + (size_t)NN * H2;      // [NN*H2]

    int eb = (E + 255) / 256;
    k_gemm1<<<NN / 64, 256, 0, stream>>>(feat, W1, P, deg_out_cnt); // zeroes deg too
    k_degree<<<eb, 256, 0, stream>>>(src, dst, deg_out_cnt, deg_in, E);
    k_scan<<<1, 1024, 0, stream>>>(deg_out_cnt, deg_in, row_ptr, n_src, n_dst);
    k_scatter<<<eb, 256, 0, stream>>>(src, dst, row_ptr, deg_out_cnt, sorted_src, E);
    k_agg1<<<NN / 8, 256, 0, stream>>>(row_ptr, sorted_src, P, n_src, n_dst, b1, h1s);
    k_agg2<<<NN / 8, 256, 0, stream>>>(row_ptr, sorted_src, h1s, n_dst, W2, b2, W3, b3, mu, lv);

    dim3 grid(NN / TILE, NN / TILE);
    k_adj<<<grid, 256, 0, stream>>>(mu, adj);
}